// Round 11
// baseline (219.766 us; speedup 1.0000x reference)
//
#include <hip/hip_runtime.h>
#include <cstdio>

typedef __attribute__((ext_vector_type(8))) short short8;
typedef __attribute__((ext_vector_type(4))) float f32x4;

// ---------- helpers ----------

__device__ __forceinline__ unsigned short bf16r(float f) {
  union { float f; unsigned int u; } x; x.f = f;
  unsigned int r = x.u + 0x7fffu + ((x.u >> 16) & 1u);
  return (unsigned short)(r >> 16);
}

__device__ __forceinline__ float bf16f(unsigned short h) {
  union { unsigned int u; float f; } x; x.u = ((unsigned int)h) << 16;
  return x.f;
}

__device__ __forceinline__ void gload_lds16(const void* g, void* l) {
  __builtin_amdgcn_global_load_lds((const __attribute__((address_space(1))) void*)g,
                                   (__attribute__((address_space(3))) void*)l,
                                   16, 0, 0);
}

__device__ __forceinline__ short8 pack_bf16(float4 f0, float4 f1) {
  short8 h;
  h[0] = (short)bf16r(f0.x); h[1] = (short)bf16r(f0.y);
  h[2] = (short)bf16r(f0.z); h[3] = (short)bf16r(f0.w);
  h[4] = (short)bf16r(f1.x); h[5] = (short)bf16r(f1.y);
  h[6] = (short)bf16r(f1.z); h[7] = (short)bf16r(f1.w);
  return h;
}

// ---------- q_w [4096][4096] f32 -> qwt2 [4096(j)][8192] bf16: cols 0..4095 = hi(q_w^T), 4096.. = lo ----------

__global__ void transpose_hilo(const float* __restrict__ in, unsigned short* __restrict__ out) {
  __shared__ float tile[64][65];
  const int j0 = blockIdx.x * 64, i0 = blockIdx.y * 64;
  const int tx = threadIdx.x & 15, ty = threadIdx.x >> 4;
  #pragma unroll
  for (int w = 0; w < 4; ++w) {
    int r = ty + w * 16;
    float4 v = *reinterpret_cast<const float4*>(in + (size_t)(i0 + r) * 4096 + j0 + tx * 4);
    tile[r][tx * 4 + 0] = v.x; tile[r][tx * 4 + 1] = v.y;
    tile[r][tx * 4 + 2] = v.z; tile[r][tx * 4 + 3] = v.w;
  }
  __syncthreads();
  #pragma unroll
  for (int w = 0; w < 4; ++w) {
    int r = ty + w * 16;   // j offset within tile
    float v0 = tile[tx * 4 + 0][r], v1 = tile[tx * 4 + 1][r];
    float v2 = tile[tx * 4 + 2][r], v3 = tile[tx * 4 + 3][r];
    ushort4 hi, lo;
    hi.x = bf16r(v0); lo.x = bf16r(v0 - bf16f(hi.x));
    hi.y = bf16r(v1); lo.y = bf16r(v1 - bf16f(hi.y));
    hi.z = bf16r(v2); lo.z = bf16r(v2 - bf16f(hi.z));
    hi.w = bf16r(v3); lo.w = bf16r(v3 - bf16f(hi.w));
    *reinterpret_cast<ushort4*>(out + (size_t)(j0 + r) * 8192 + i0 + tx * 4) = hi;
    *reinterpret_cast<ushort4*>(out + (size_t)(j0 + r) * 8192 + 4096 + i0 + tx * 4) = lo;
  }
}

// ---------- k_cache [100][4096] f32 -> kpad2 [128][8192] bf16 duplicated ([kpad|kpad]), rows>=100 zero ----------

__global__ void build_pad_dup(const float* __restrict__ src, unsigned short* __restrict__ dst) {
  int idx = blockIdx.x * blockDim.x + threadIdx.x;   // over 128*4096
  if (idx >= 128 * 4096) return;
  int l = idx >> 12, i = idx & 4095;
  float v = (l < 100) ? src[idx] : 0.f;
  unsigned short b = bf16r(v);
  dst[(size_t)l * 8192 + i] = b;
  dst[(size_t)l * 8192 + 4096 + i] = b;
}

// ---------- v_cache [100][4096] f32 -> vpad [128][4096] bf16, rows>=100 zero ----------

__global__ void build_pad128(const float* __restrict__ src, unsigned short* __restrict__ dst) {
  int idx = blockIdx.x * blockDim.x + threadIdx.x;
  if (idx >= 128 * 4096) return;
  int row = idx >> 12;
  float v = (row < 100) ? src[idx] : 0.f;
  dst[idx] = bf16r(v);
}

// ---------- sbias[l] = q_b . k_cache[l] (f32, exact), 0 for l>=100 ----------

__global__ void kq_bias(const float* __restrict__ kc, const float* __restrict__ qb,
                        float* __restrict__ sbias) {
  int l = blockIdx.x;            // 0..127
  int lane = threadIdx.x;        // 64
  float s = 0.f;
  if (l < 100) {
    for (int i = lane * 4; i < 4096; i += 256) {
      float4 k = *reinterpret_cast<const float4*>(kc + (size_t)l * 4096 + i);
      float4 q = *reinterpret_cast<const float4*>(qb + i);
      s += k.x * q.x + k.y * q.y + k.z * q.z + k.w * q.w;
    }
  }
  #pragma unroll
  for (int off = 1; off < 64; off <<= 1) s += __shfl_xor(s, off);
  if (lane == 0) sbias[l] = s;
}

// ---------- split-K NT GEMM, bf16 A x bf16 B (both gload_lds) -> f32 partials (KQ GEMM) ----------

__global__ void gemm_ntk_splitk(const unsigned short* __restrict__ A,
                                const unsigned short* __restrict__ B,
                                float* __restrict__ Cpart,
                                int M, int N, int Kstride, int kchunk) {
  __shared__ unsigned short As[128][32];
  __shared__ unsigned short Bs[128][32];

  const int tid = threadIdx.x, wave = tid >> 6, lane = tid & 63;
  const int wm = wave >> 1, wn = wave & 1;
  const size_t rowA0 = (size_t)blockIdx.y * 128;
  const size_t colB0 = (size_t)blockIdx.z * 128;
  const int k0base = blockIdx.x * kchunk;

  f32x4 acc[4][4] = {};

  const int sr = wave * 16 + (lane >> 2);
  const int sc = (lane & 3) << 3;

  const unsigned short* Ap0 = A + (rowA0 + sr) * (size_t)Kstride + k0base + sc;
  const unsigned short* Ap1 = A + (rowA0 + 64 + sr) * (size_t)Kstride + k0base + sc;
  const unsigned short* Bp0 = B + (colB0 + sr) * (size_t)Kstride + k0base + sc;
  const unsigned short* Bp1 = B + (colB0 + 64 + sr) * (size_t)Kstride + k0base + sc;
  unsigned short* AsD0 = &As[wave * 16][0];
  unsigned short* AsD1 = &As[64 + wave * 16][0];
  unsigned short* BsD0 = &Bs[wave * 16][0];
  unsigned short* BsD1 = &Bs[64 + wave * 16][0];

  const int fr = lane & 15;
  const int fk = (lane >> 4) << 3;

  for (int k0 = 0; k0 < kchunk; k0 += 32) {
    gload_lds16(Ap0 + k0, AsD0);
    gload_lds16(Ap1 + k0, AsD1);
    gload_lds16(Bp0 + k0, BsD0);
    gload_lds16(Bp1 + k0, BsD1);
    __syncthreads();

    short8 av[4], bv[4];
    #pragma unroll
    for (int mi = 0; mi < 4; ++mi)
      av[mi] = *reinterpret_cast<const short8*>(&As[wm * 64 + mi * 16 + fr][fk]);
    #pragma unroll
    for (int ni = 0; ni < 4; ++ni)
      bv[ni] = *reinterpret_cast<const short8*>(&Bs[wn * 64 + ni * 16 + fr][fk]);
    #pragma unroll
    for (int mi = 0; mi < 4; ++mi)
      #pragma unroll
      for (int ni = 0; ni < 4; ++ni)
        acc[mi][ni] = __builtin_amdgcn_mfma_f32_16x16x32_bf16(av[mi], bv[ni], acc[mi][ni], 0, 0, 0);
    __syncthreads();
  }

  float* Cp = Cpart + (size_t)blockIdx.x * M * N;
  const int orow = (lane >> 4) * 4;
  const int ocol = lane & 15;
  #pragma unroll
  for (int mi = 0; mi < 4; ++mi) {
    #pragma unroll
    for (int ni = 0; ni < 4; ++ni) {
      size_t r0 = rowA0 + wm * 64 + mi * 16 + orow;
      size_t c  = colB0 + wn * 64 + ni * 16 + ocol;
      #pragma unroll
      for (int j = 0; j < 4; ++j)
        Cp[(r0 + j) * (size_t)N + c] = acc[mi][ni][j];
    }
  }
}

// ---------- PADDED-LDS reg-staged NT GEMM (conflict-free) ----------
// 128x128 tile, 4 waves (2x2), acc[4][4], BK=32. LDS rows padded to 40 elements
// (80 B = 20 banks) so each 8-lane b128 service phase hits 8 distinct 4-bank
// groups {0,20,8,28,16,4,24,12} -> conflict-free reads, ~2-way writes.
// Both operands reg-staged (NO global_load_lds -> padding is legal, m173).
// AF32: A is f32, converted to bf16 in-reg. FINAL: single-K, +bias, direct f32 out.
// Non-FINAL: blockIdx.x = (ks << ntShift) | ntile; Cpart[ks][M][N]. N = output row width.

template<bool AF32, bool FINAL>
__global__ __launch_bounds__(256)
void gemm_pad(const void* __restrict__ Avoid,
              const unsigned short* __restrict__ B,
              const float* __restrict__ bias,
              float* __restrict__ Cout,
              int M, int N, int Kstride, int kchunk, int ntShift) {
  __shared__ unsigned short As[128][40];   // 10 KB
  __shared__ unsigned short Bs[128][40];   // 10 KB

  const int tid = threadIdx.x, wave = tid >> 6, lane = tid & 63;
  const int wm = wave >> 1, wn = wave & 1;
  const int ks    = FINAL ? 0 : (blockIdx.x >> ntShift);
  const int ntile = FINAL ? blockIdx.x : (blockIdx.x & ((1 << ntShift) - 1));
  const size_t rowA0 = (size_t)blockIdx.y * 128;
  const size_t colB0 = (size_t)ntile * 128;
  const int k0base = ks * kchunk;

  f32x4 acc[4][4] = {};

  const int srow  = tid >> 1;          // 0..127
  const int shalf = (tid & 1) * 16;    // element offset within 32-wide step

  const float* Af          = (const float*)Avoid;
  const unsigned short* Ab = (const unsigned short*)Avoid;
  const float* ApF          = AF32 ? Af + (rowA0 + srow) * (size_t)Kstride + k0base + shalf : nullptr;
  const unsigned short* ApB = AF32 ? nullptr : Ab + (rowA0 + srow) * (size_t)Kstride + k0base + shalf;
  const unsigned short* Bp  = B + (colB0 + srow) * (size_t)Kstride + k0base + shalf;

  const int fr = lane & 15;
  const int fk = (lane >> 4) << 3;     // 0,8,16,24

  for (int k0 = 0; k0 < kchunk; k0 += 32) {
    // stage B (L2-resident operand) via regs
    short8 b0 = *reinterpret_cast<const short8*>(Bp + k0);
    short8 b1 = *reinterpret_cast<const short8*>(Bp + k0 + 8);
    // stage A
    short8 h0, h1;
    if (AF32) {
      float4 f0 = *reinterpret_cast<const float4*>(ApF + k0);
      float4 f1 = *reinterpret_cast<const float4*>(ApF + k0 + 4);
      float4 f2 = *reinterpret_cast<const float4*>(ApF + k0 + 8);
      float4 f3 = *reinterpret_cast<const float4*>(ApF + k0 + 12);
      h0 = pack_bf16(f0, f1);
      h1 = pack_bf16(f2, f3);
    } else {
      h0 = *reinterpret_cast<const short8*>(ApB + k0);
      h1 = *reinterpret_cast<const short8*>(ApB + k0 + 8);
    }
    *reinterpret_cast<short8*>(&As[srow][shalf])     = h0;
    *reinterpret_cast<short8*>(&As[srow][shalf + 8]) = h1;
    *reinterpret_cast<short8*>(&Bs[srow][shalf])     = b0;
    *reinterpret_cast<short8*>(&Bs[srow][shalf + 8]) = b1;
    __syncthreads();

    short8 av[4], bv[4];
    #pragma unroll
    for (int mi = 0; mi < 4; ++mi)
      av[mi] = *reinterpret_cast<const short8*>(&As[wm * 64 + mi * 16 + fr][fk]);
    #pragma unroll
    for (int ni = 0; ni < 4; ++ni)
      bv[ni] = *reinterpret_cast<const short8*>(&Bs[wn * 64 + ni * 16 + fr][fk]);
    #pragma unroll
    for (int mi = 0; mi < 4; ++mi)
      #pragma unroll
      for (int ni = 0; ni < 4; ++ni)
        acc[mi][ni] = __builtin_amdgcn_mfma_f32_16x16x32_bf16(av[mi], bv[ni], acc[mi][ni], 0, 0, 0);
    __syncthreads();
  }

  float* Cp = FINAL ? Cout : Cout + (size_t)ks * M * N;
  const int orow = (lane >> 4) * 4;
  const int ocol = lane & 15;
  #pragma unroll
  for (int mi = 0; mi < 4; ++mi) {
    #pragma unroll
    for (int ni = 0; ni < 4; ++ni) {
      size_t r0 = rowA0 + wm * 64 + mi * 16 + orow;
      size_t c  = colB0 + wn * 64 + ni * 16 + ocol;
      float bv_ = FINAL ? bias[c] : 0.f;
      #pragma unroll
      for (int j = 0; j < 4; ++j)
        Cp[(r0 + j) * (size_t)N + c] = acc[mi][ni][j] + bv_;
    }
  }
}

// ---------- KQ reduce: sum 8 partials [128][4096], split hi/lo -> KQ2 [256][4096] bf16 ----------

__global__ void kq_reduce(const float* __restrict__ KQpart, unsigned short* __restrict__ KQ2) {
  int idx = blockIdx.x * blockDim.x + threadIdx.x;   // over 128*4096, idx = l*4096 + j
  if (idx >= 128 * 4096) return;
  float s = 0.f;
  #pragma unroll
  for (int ks = 0; ks < 8; ++ks) s += KQpart[(size_t)ks * 128 * 4096 + idx];
  unsigned short hi = bf16r(s);
  unsigned short lo = bf16r(s - bf16f(hi));
  int l = idx >> 12, j = idx & 4095;
  KQ2[(size_t)l * 4096 + j]         = hi;
  KQ2[(size_t)(l + 128) * 4096 + j] = lo;
}

// ---------- softmax: sum 4 ks-partials + hi/lo col fold + bias -> duplicated [W|W] bf16 [rows][256] ----------

__global__ void softmax_fused2(const float* __restrict__ Spart, const float* __restrict__ sbias,
                               unsigned short* __restrict__ W2, int rows) {
  int wave = threadIdx.x >> 6;
  int lane = threadIdx.x & 63;
  int row = blockIdx.x * (blockDim.x >> 6) + wave;
  if (row >= rows) return;
  const float scale = 0.088388347648318447f;   // 1/sqrt(128)
  float sx = 0.f, sy = 0.f;
  #pragma unroll
  for (int ks = 0; ks < 4; ++ks) {
    const float* P = Spart + ((size_t)ks * rows + row) * 256;
    float2 a = reinterpret_cast<const float2*>(P)[lane];          // hi cols
    float2 b = reinterpret_cast<const float2*>(P + 128)[lane];    // lo cols
    sx += a.x + b.x; sy += a.y + b.y;
  }
  float2 bb = reinterpret_cast<const float2*>(sbias)[lane];
  sx += bb.x; sy += bb.y;
  int c0 = lane * 2, c1 = c0 + 1;
  float s0 = (c0 <= 100) ? sx * scale : -1e30f;
  float s1 = (c1 <= 100) ? sy * scale : -1e30f;
  float m = fmaxf(s0, s1);
  #pragma unroll
  for (int off = 1; off < 64; off <<= 1) m = fmaxf(m, __shfl_xor(m, off));
  float e0 = (c0 <= 100) ? __expf(s0 - m) : 0.f;
  float e1 = (c1 <= 100) ? __expf(s1 - m) : 0.f;
  float sum = e0 + e1;
  #pragma unroll
  for (int off = 1; off < 64; off <<= 1) sum += __shfl_xor(sum, off);
  float inv = 1.f / sum;
  ushort2 o;
  o.x = bf16r(e0 * inv);
  o.y = bf16r(e1 * inv);
  reinterpret_cast<ushort2*>(W2 + (size_t)row * 256)[lane] = o;
  reinterpret_cast<ushort2*>(W2 + (size_t)row * 256 + 128)[lane] = o;
}

// ---------- VO reduce: sum 16 partials [4096][128], split hi/lo -> VOT2 [4096][256] bf16 ----------

__global__ void vo_reduce(const float* __restrict__ VOpart, unsigned short* __restrict__ VOT2) {
  int idx = blockIdx.x * blockDim.x + threadIdx.x;   // over 4096*128, idx = o*128 + l
  if (idx >= 4096 * 128) return;
  float s = 0.f;
  #pragma unroll
  for (int ks = 0; ks < 16; ++ks) s += VOpart[(size_t)ks * 4096 * 128 + idx];
  unsigned short hi = bf16r(s);
  unsigned short lo = bf16r(s - bf16f(hi));
  int o = idx >> 7, l = idx & 127;
  VOT2[(size_t)o * 256 + l]       = hi;
  VOT2[(size_t)o * 256 + 128 + l] = lo;
}

// ---------- launch ----------

extern "C" void kernel_launch(void* const* d_in, const int* in_sizes, int n_in,
                              void* d_out, int out_size, void* d_ws, size_t ws_size,
                              hipStream_t stream) {
  const float* x       = (const float*)d_in[0];   // [8192,4096]
  const float* q_w     = (const float*)d_in[1];   // [4096,4096]
  const float* q_b     = (const float*)d_in[2];   // [4096]
  const float* k_cache = (const float*)d_in[3];   // [100,4096]
  const float* v_cache = (const float*)d_in[4];   // [100,4096]
  const float* out_w   = (const float*)d_in[5];   // [4096,4096]
  const float* out_b   = (const float*)d_in[6];   // [4096]
  float* out = (float*)d_out;

  const int M = 8192, H = 4096;

  char* ws = (char*)d_ws;
  size_t off = 0;
  auto alloc = [&](size_t bytes) { void* p = ws + off; off += (bytes + 255) & ~(size_t)255; return p; };
  unsigned short* qwt2   = (unsigned short*)alloc((size_t)H * 8192 * 2);   // 67 MB  q_w^T hi|lo
  unsigned short* kpad2  = (unsigned short*)alloc((size_t)128 * 8192 * 2); // 2 MB   [kpad|kpad]
  unsigned short* vpad   = (unsigned short*)alloc((size_t)128 * H * 2);    // 1 MB
  float*          sbias  = (float*)alloc(128 * 4);
  unsigned short* KQ2    = (unsigned short*)alloc((size_t)256 * H * 2);    // 2 MB   [KQ_hi;KQ_lo]
  unsigned short* W2     = (unsigned short*)alloc((size_t)M * 256 * 2);    // 4 MB   [W|W]
  unsigned short* VOT2   = (unsigned short*)alloc((size_t)H * 256 * 2);    // 2 MB   [VO^T hi|lo]
  float*          scratch= (float*)alloc((size_t)36 << 20);                // 36 MB  partials
  if (ws_size < off) { fprintf(stderr, "ws too small: need %zu have %zu\n", off, ws_size); return; }

  // 1) weight/cache preprocessing
  transpose_hilo<<<dim3(64, 64), 256, 0, stream>>>(q_w, qwt2);
  build_pad_dup<<<2048, 256, 0, stream>>>(k_cache, kpad2);
  build_pad128<<<2048, 256, 0, stream>>>(v_cache, vpad);
  kq_bias<<<128, 64, 0, stream>>>(k_cache, q_b, sbias);

  // 2) KQ = kpad @ q_w  (via [kpad|kpad] @ [qwt_hi|qwt_lo]^T, K=8192), split-K 8
  gemm_ntk_splitk<<<dim3(8, 1, 32), 256, 0, stream>>>(kpad2, qwt2, scratch, 128, H, 8192, 1024);
  kq_reduce<<<2048, 256, 0, stream>>>(scratch, KQ2);

  // 3) S = x @ KQ2^T (N=256 hi/lo planes), padded-LDS kernel, split-K 4 -> 512 blocks
  gemm_pad<true, false><<<dim3(8, 64), 256, 0, stream>>>(
      x, KQ2, nullptr, scratch, M, 256, H, 1024, 1);

  // 4) softmax (4 ks partials + hi/lo fold + bias) -> W2 [8192][256] dup
  softmax_fused2<<<M / 4, 256, 0, stream>>>(scratch, sbias, W2, M);

  // 5) VO^T = out_w @ vpad^T, padded-LDS kernel, split-K 16 -> 512 blocks
  gemm_pad<true, false><<<dim3(16, 32), 256, 0, stream>>>(
      out_w, vpad, nullptr, scratch, H, 128, H, 256, 0);
  vo_reduce<<<2048, 256, 0, stream>>>(scratch, VOT2);

  // 6) out = W2 @ VOT2^T + out_b  (K=256: [W|W] x [hi|lo]), padded-LDS kernel
  gemm_pad<false, true><<<dim3(32, 64), 256, 0, stream>>>(
      W2, VOT2, out_b, out, M, H, 256, 256, 0);
}

// Round 12
// 201.486 us; speedup vs baseline: 1.0907x; 1.0907x over previous
//
#include <hip/hip_runtime.h>
#include <cstdio>

typedef __attribute__((ext_vector_type(8))) short short8;
typedef __attribute__((ext_vector_type(4))) float f32x4;

// ---------- helpers ----------

__device__ __forceinline__ unsigned short bf16r(float f) {
  union { float f; unsigned int u; } x; x.f = f;
  unsigned int r = x.u + 0x7fffu + ((x.u >> 16) & 1u);
  return (unsigned short)(r >> 16);
}

__device__ __forceinline__ float bf16f(unsigned short h) {
  union { unsigned int u; float f; } x; x.u = ((unsigned int)h) << 16;
  return x.f;
}

__device__ __forceinline__ void gload_lds16(const void* g, void* l) {
  __builtin_amdgcn_global_load_lds((const __attribute__((address_space(1))) void*)g,
                                   (__attribute__((address_space(3))) void*)l,
                                   16, 0, 0);
}

__device__ __forceinline__ short8 pack_bf16(float4 f0, float4 f1) {
  short8 h;
  h[0] = (short)bf16r(f0.x); h[1] = (short)bf16r(f0.y);
  h[2] = (short)bf16r(f0.z); h[3] = (short)bf16r(f0.w);
  h[4] = (short)bf16r(f1.x); h[5] = (short)bf16r(f1.y);
  h[6] = (short)bf16r(f1.z); h[7] = (short)bf16r(f1.w);
  return h;
}

// ---------- q_w [4096][4096] f32 -> qwt2 [4096(j)][8192] bf16 (hi|lo of q_w^T) ----------

__global__ void transpose_hilo(const float* __restrict__ in, unsigned short* __restrict__ out) {
  __shared__ float tile[64][65];
  const int j0 = blockIdx.x * 64, i0 = blockIdx.y * 64;
  const int tx = threadIdx.x & 15, ty = threadIdx.x >> 4;
  #pragma unroll
  for (int w = 0; w < 4; ++w) {
    int r = ty + w * 16;
    float4 v = *reinterpret_cast<const float4*>(in + (size_t)(i0 + r) * 4096 + j0 + tx * 4);
    tile[r][tx * 4 + 0] = v.x; tile[r][tx * 4 + 1] = v.y;
    tile[r][tx * 4 + 2] = v.z; tile[r][tx * 4 + 3] = v.w;
  }
  __syncthreads();
  #pragma unroll
  for (int w = 0; w < 4; ++w) {
    int r = ty + w * 16;
    float v0 = tile[tx * 4 + 0][r], v1 = tile[tx * 4 + 1][r];
    float v2 = tile[tx * 4 + 2][r], v3 = tile[tx * 4 + 3][r];
    ushort4 hi, lo;
    hi.x = bf16r(v0); lo.x = bf16r(v0 - bf16f(hi.x));
    hi.y = bf16r(v1); lo.y = bf16r(v1 - bf16f(hi.y));
    hi.z = bf16r(v2); lo.z = bf16r(v2 - bf16f(hi.z));
    hi.w = bf16r(v3); lo.w = bf16r(v3 - bf16f(hi.w));
    *reinterpret_cast<ushort4*>(out + (size_t)(j0 + r) * 8192 + i0 + tx * 4) = hi;
    *reinterpret_cast<ushort4*>(out + (size_t)(j0 + r) * 8192 + 4096 + i0 + tx * 4) = lo;
  }
}

// ---------- cache prep ----------

__global__ void build_pad_dup(const float* __restrict__ src, unsigned short* __restrict__ dst) {
  int idx = blockIdx.x * blockDim.x + threadIdx.x;
  if (idx >= 128 * 4096) return;
  int l = idx >> 12, i = idx & 4095;
  float v = (l < 100) ? src[idx] : 0.f;
  unsigned short b = bf16r(v);
  dst[(size_t)l * 8192 + i] = b;
  dst[(size_t)l * 8192 + 4096 + i] = b;
}

__global__ void build_pad128(const float* __restrict__ src, unsigned short* __restrict__ dst) {
  int idx = blockIdx.x * blockDim.x + threadIdx.x;
  if (idx >= 128 * 4096) return;
  int row = idx >> 12;
  float v = (row < 100) ? src[idx] : 0.f;
  dst[idx] = bf16r(v);
}

__global__ void kq_bias(const float* __restrict__ kc, const float* __restrict__ qb,
                        float* __restrict__ sbias) {
  int l = blockIdx.x;
  int lane = threadIdx.x;
  float s = 0.f;
  if (l < 100) {
    for (int i = lane * 4; i < 4096; i += 256) {
      float4 k = *reinterpret_cast<const float4*>(kc + (size_t)l * 4096 + i);
      float4 q = *reinterpret_cast<const float4*>(qb + i);
      s += k.x * q.x + k.y * q.y + k.z * q.z + k.w * q.w;
    }
  }
  #pragma unroll
  for (int off = 1; off < 64; off <<= 1) s += __shfl_xor(s, off);
  if (lane == 0) sbias[l] = s;
}

// ---------- split-K NT GEMM, bf16 x bf16 (KQ GEMM), r5-proven ----------

__global__ void gemm_ntk_splitk(const unsigned short* __restrict__ A,
                                const unsigned short* __restrict__ B,
                                float* __restrict__ Cpart,
                                int M, int N, int Kstride, int kchunk) {
  __shared__ unsigned short As[128][32];
  __shared__ unsigned short Bs[128][32];

  const int tid = threadIdx.x, wave = tid >> 6, lane = tid & 63;
  const int wm = wave >> 1, wn = wave & 1;
  const size_t rowA0 = (size_t)blockIdx.y * 128;
  const size_t colB0 = (size_t)blockIdx.z * 128;
  const int k0base = blockIdx.x * kchunk;

  f32x4 acc[4][4] = {};

  const int sr = wave * 16 + (lane >> 2);
  const int sc = (lane & 3) << 3;

  const unsigned short* Ap0 = A + (rowA0 + sr) * (size_t)Kstride + k0base + sc;
  const unsigned short* Ap1 = A + (rowA0 + 64 + sr) * (size_t)Kstride + k0base + sc;
  const unsigned short* Bp0 = B + (colB0 + sr) * (size_t)Kstride + k0base + sc;
  const unsigned short* Bp1 = B + (colB0 + 64 + sr) * (size_t)Kstride + k0base + sc;
  unsigned short* AsD0 = &As[wave * 16][0];
  unsigned short* AsD1 = &As[64 + wave * 16][0];
  unsigned short* BsD0 = &Bs[wave * 16][0];
  unsigned short* BsD1 = &Bs[64 + wave * 16][0];

  const int fr = lane & 15;
  const int fk = (lane >> 4) << 3;

  for (int k0 = 0; k0 < kchunk; k0 += 32) {
    gload_lds16(Ap0 + k0, AsD0);
    gload_lds16(Ap1 + k0, AsD1);
    gload_lds16(Bp0 + k0, BsD0);
    gload_lds16(Bp1 + k0, BsD1);
    __syncthreads();

    short8 av[4], bv[4];
    #pragma unroll
    for (int mi = 0; mi < 4; ++mi)
      av[mi] = *reinterpret_cast<const short8*>(&As[wm * 64 + mi * 16 + fr][fk]);
    #pragma unroll
    for (int ni = 0; ni < 4; ++ni)
      bv[ni] = *reinterpret_cast<const short8*>(&Bs[wn * 64 + ni * 16 + fr][fk]);
    #pragma unroll
    for (int mi = 0; mi < 4; ++mi)
      #pragma unroll
      for (int ni = 0; ni < 4; ++ni)
        acc[mi][ni] = __builtin_amdgcn_mfma_f32_16x16x32_bf16(av[mi], bv[ni], acc[mi][ni], 0, 0, 0);
    __syncthreads();
  }

  float* Cp = Cpart + (size_t)blockIdx.x * M * N;
  const int orow = (lane >> 4) * 4;
  const int ocol = lane & 15;
  #pragma unroll
  for (int mi = 0; mi < 4; ++mi) {
    #pragma unroll
    for (int ni = 0; ni < 4; ++ni) {
      size_t r0 = rowA0 + wm * 64 + mi * 16 + orow;
      size_t c  = colB0 + wn * 64 + ni * 16 + ocol;
      #pragma unroll
      for (int j = 0; j < 4; ++j)
        Cp[(r0 + j) * (size_t)N + c] = acc[mi][ni][j];
    }
  }
}

// ---------- PIPELINED streaming GEMM (counted-vmcnt, r3-derived schedule) ----------
// f32 A streamed (staged raw via gload_lds, cvt at frag read), bf16 B (L2-resident).
// 128x128 output tile, BK=32, 4 waves (2x2). NB = B rows (256 -> hi/lo fold, 128 plain).
// LDS dbuf; per iter: read frags buf[c]; lgkmcnt(0); barrier; stage(k+2)->buf[c];
// MFMA; vmcnt(stage-ops) [waits only stage k+1]; barrier. vmcnt never 0 in loop.
// A slot-swizzle: 16B slot s of row r at s^(r&7) (inverse-permuted global source).
// B slot-swizzle: s^(r&3) over 4 slots.

template<int NB>
__global__ __launch_bounds__(256, 1)
void gemm_sv(const float* __restrict__ A, const unsigned short* __restrict__ B,
             float* __restrict__ Cpart, int M, int Kstride, int kchunk) {
  constexpr int FOLD = NB / 128;
  __shared__ float          As[2][128][32];   // 32 KB
  __shared__ unsigned short Bs[2][NB][32];    // 32 / 16 KB

  const int tid = threadIdx.x, wave = tid >> 6, lane = tid & 63;
  const int wm = wave >> 1, wn = wave & 1;
  const int ks = blockIdx.x, mblk = blockIdx.y;
  const size_t rowA0 = (size_t)mblk * 128;
  const int k0 = ks * kchunk;
  const int nsteps = kchunk >> 5;

  // A staging: 4 issues/wave x 8 rows; lane -> row (lane>>3), global slot inv-swizzled
  const int ar = lane >> 3;
  const int as_g = (lane & 7) ^ ar;          // ar in 0..7
  // B staging: NB/64 issues/wave x 16 rows
  const int br = lane >> 2;
  const int bs_g = (lane & 3) ^ (br & 3);

#define STAGE_SV(kt, BUF) do { \
    const int _kc = k0 + (kt) * 32; \
    _Pragma("unroll") \
    for (int j = 0; j < 4; ++j) \
      gload_lds16(A + (rowA0 + wave * 32 + j * 8 + ar) * (size_t)Kstride + _kc + as_g * 4, \
                  &As[BUF][wave * 32 + j * 8][0]); \
    _Pragma("unroll") \
    for (int j = 0; j < NB / 64; ++j) \
      gload_lds16(B + (size_t)(wave * (NB / 4) + j * 16 + br) * Kstride + _kc + bs_g * 8, \
                  &Bs[BUF][wave * (NB / 4) + j * 16][0]); \
  } while (0)

#define WAIT_STAGE do { \
    if (NB == 256) asm volatile("s_waitcnt vmcnt(8)" ::: "memory"); \
    else           asm volatile("s_waitcnt vmcnt(6)" ::: "memory"); \
  } while (0)

  const int fr = lane & 15, kq = lane >> 4;
  f32x4 acc[4][4] = {};

  // prologue: stage step0 -> buf0, step1 -> buf1; wait step0; barrier
  STAGE_SV(0, 0);
  STAGE_SV(1, 1);
  WAIT_STAGE;
  asm volatile("" ::: "memory");
  __builtin_amdgcn_s_barrier();
  asm volatile("" ::: "memory");

  for (int k = 0; k < nsteps; ++k) {
    const int c = k & 1;

    // frag reads from buf[c] (plain C; drained before barrier below)
    short8 av[4], bv[4][FOLD];
    #pragma unroll
    for (int mi = 0; mi < 4; ++mi) {
      const float* rp = &As[c][wm * 64 + mi * 16 + fr][0];
      float4 f0 = *reinterpret_cast<const float4*>(rp + (((2 * kq)     ^ (fr & 7)) * 4));
      float4 f1 = *reinterpret_cast<const float4*>(rp + (((2 * kq + 1) ^ (fr & 7)) * 4));
      av[mi] = pack_bf16(f0, f1);
    }
    #pragma unroll
    for (int ni = 0; ni < 4; ++ni)
      #pragma unroll
      for (int p = 0; p < FOLD; ++p) {
        int rb = p * 128 + wn * 64 + ni * 16 + fr;
        bv[ni][p] = *reinterpret_cast<const short8*>(&Bs[c][rb][0] + ((kq ^ (fr & 3)) * 8));
      }

    asm volatile("s_waitcnt lgkmcnt(0)" ::: "memory");   // my reads drained
    __builtin_amdgcn_s_barrier();                        // all waves' reads done
    asm volatile("" ::: "memory");

    const int kt2 = (k + 2 < nsteps) ? k + 2 : nsteps - 1;
    STAGE_SV(kt2, c);                                    // overwrite just-freed buffer
    asm volatile("" ::: "memory");

    __builtin_amdgcn_s_setprio(1);
    #pragma unroll
    for (int mi = 0; mi < 4; ++mi)
      #pragma unroll
      for (int ni = 0; ni < 4; ++ni)
        #pragma unroll
        for (int p = 0; p < FOLD; ++p)
          acc[mi][ni] = __builtin_amdgcn_mfma_f32_16x16x32_bf16(av[mi], bv[ni][p], acc[mi][ni], 0, 0, 0);
    __builtin_amdgcn_s_setprio(0);

    WAIT_STAGE;                                          // stage(k+1) landed; k+2 stays in flight
    asm volatile("" ::: "memory");
    __builtin_amdgcn_s_barrier();                        // buf[n] ready for next iter
    asm volatile("" ::: "memory");
  }

#undef STAGE_SV
#undef WAIT_STAGE

  float* Cp = Cpart + (size_t)ks * M * 128;
  const int orow = (lane >> 4) * 4;
  const int ocol = lane & 15;
  #pragma unroll
  for (int mi = 0; mi < 4; ++mi) {
    #pragma unroll
    for (int ni = 0; ni < 4; ++ni) {
      size_t r0 = rowA0 + wm * 64 + mi * 16 + orow;
      size_t c  = (size_t)wn * 64 + ni * 16 + ocol;
      #pragma unroll
      for (int j = 0; j < 4; ++j)
        Cp[(r0 + j) * 128 + c] = acc[mi][ni][j];
    }
  }
}

// ---------- KQ reduce (8 partials) ----------

__global__ void kq_reduce(const float* __restrict__ KQpart, unsigned short* __restrict__ KQ2) {
  int idx = blockIdx.x * blockDim.x + threadIdx.x;
  if (idx >= 128 * 4096) return;
  float s = 0.f;
  #pragma unroll
  for (int ks = 0; ks < 8; ++ks) s += KQpart[(size_t)ks * 128 * 4096 + idx];
  unsigned short hi = bf16r(s);
  unsigned short lo = bf16r(s - bf16f(hi));
  int l = idx >> 12, j = idx & 4095;
  KQ2[(size_t)l * 4096 + j]         = hi;
  KQ2[(size_t)(l + 128) * 4096 + j] = lo;
}

// ---------- softmax: sum 8 ks-partials (width 128, planes pre-folded) + bias ----------

__global__ void softmax_fused2(const float* __restrict__ Spart, const float* __restrict__ sbias,
                               unsigned short* __restrict__ W2, int rows) {
  int wave = threadIdx.x >> 6;
  int lane = threadIdx.x & 63;
  int row = blockIdx.x * (blockDim.x >> 6) + wave;
  if (row >= rows) return;
  const float scale = 0.088388347648318447f;
  float sx = 0.f, sy = 0.f;
  #pragma unroll
  for (int ks = 0; ks < 8; ++ks) {
    float2 p = reinterpret_cast<const float2*>(Spart + ((size_t)ks * rows + row) * 128)[lane];
    sx += p.x; sy += p.y;
  }
  float2 bb = reinterpret_cast<const float2*>(sbias)[lane];
  sx += bb.x; sy += bb.y;
  int c0 = lane * 2, c1 = c0 + 1;
  float s0 = (c0 <= 100) ? sx * scale : -1e30f;
  float s1 = (c1 <= 100) ? sy * scale : -1e30f;
  float m = fmaxf(s0, s1);
  #pragma unroll
  for (int off = 1; off < 64; off <<= 1) m = fmaxf(m, __shfl_xor(m, off));
  float e0 = (c0 <= 100) ? __expf(s0 - m) : 0.f;
  float e1 = (c1 <= 100) ? __expf(s1 - m) : 0.f;
  float sum = e0 + e1;
  #pragma unroll
  for (int off = 1; off < 64; off <<= 1) sum += __shfl_xor(sum, off);
  float inv = 1.f / sum;
  ushort2 o;
  o.x = bf16r(e0 * inv);
  o.y = bf16r(e1 * inv);
  reinterpret_cast<ushort2*>(W2 + (size_t)row * 256)[lane] = o;
  reinterpret_cast<ushort2*>(W2 + (size_t)row * 256 + 128)[lane] = o;
}

// ---------- VO reduce (16 partials) ----------

__global__ void vo_reduce(const float* __restrict__ VOpart, unsigned short* __restrict__ VOT2) {
  int idx = blockIdx.x * blockDim.x + threadIdx.x;
  if (idx >= 4096 * 128) return;
  float s = 0.f;
  #pragma unroll
  for (int ks = 0; ks < 16; ++ks) s += VOpart[(size_t)ks * 4096 * 128 + idx];
  unsigned short hi = bf16r(s);
  unsigned short lo = bf16r(s - bf16f(hi));
  int o = idx >> 7, l = idx & 127;
  VOT2[(size_t)o * 256 + l]       = hi;
  VOT2[(size_t)o * 256 + 128 + l] = lo;
}

// ---------- padded-LDS reg-staged GEMM (final: out = W2 @ VOT2^T + out_b) ----------

__global__ __launch_bounds__(256)
void gemm_final(const unsigned short* __restrict__ A,
                const unsigned short* __restrict__ B,
                const float* __restrict__ bias,
                float* __restrict__ Cout,
                int M, int N, int K) {
  __shared__ unsigned short As[128][40];
  __shared__ unsigned short Bs[128][40];

  const int tid = threadIdx.x, wave = tid >> 6, lane = tid & 63;
  const int wm = wave >> 1, wn = wave & 1;
  const size_t rowA0 = (size_t)blockIdx.y * 128;
  const size_t colB0 = (size_t)blockIdx.x * 128;

  f32x4 acc[4][4] = {};

  const int srow  = tid >> 1;
  const int shalf = (tid & 1) * 16;

  const unsigned short* Ap = A + (rowA0 + srow) * (size_t)K + shalf;
  const unsigned short* Bp = B + (colB0 + srow) * (size_t)K + shalf;

  const int fr = lane & 15;
  const int fk = (lane >> 4) << 3;

  for (int k0 = 0; k0 < K; k0 += 32) {
    short8 a0 = *reinterpret_cast<const short8*>(Ap + k0);
    short8 a1 = *reinterpret_cast<const short8*>(Ap + k0 + 8);
    short8 b0 = *reinterpret_cast<const short8*>(Bp + k0);
    short8 b1 = *reinterpret_cast<const short8*>(Bp + k0 + 8);
    *reinterpret_cast<short8*>(&As[srow][shalf])     = a0;
    *reinterpret_cast<short8*>(&As[srow][shalf + 8]) = a1;
    *reinterpret_cast<short8*>(&Bs[srow][shalf])     = b0;
    *reinterpret_cast<short8*>(&Bs[srow][shalf + 8]) = b1;
    __syncthreads();

    short8 av[4], bv[4];
    #pragma unroll
    for (int mi = 0; mi < 4; ++mi)
      av[mi] = *reinterpret_cast<const short8*>(&As[wm * 64 + mi * 16 + fr][fk]);
    #pragma unroll
    for (int ni = 0; ni < 4; ++ni)
      bv[ni] = *reinterpret_cast<const short8*>(&Bs[wn * 64 + ni * 16 + fr][fk]);
    #pragma unroll
    for (int mi = 0; mi < 4; ++mi)
      #pragma unroll
      for (int ni = 0; ni < 4; ++ni)
        acc[mi][ni] = __builtin_amdgcn_mfma_f32_16x16x32_bf16(av[mi], bv[ni], acc[mi][ni], 0, 0, 0);
    __syncthreads();
  }

  const int orow = (lane >> 4) * 4;
  const int ocol = lane & 15;
  #pragma unroll
  for (int mi = 0; mi < 4; ++mi) {
    #pragma unroll
    for (int ni = 0; ni < 4; ++ni) {
      size_t r0 = rowA0 + wm * 64 + mi * 16 + orow;
      size_t c  = colB0 + wn * 64 + ni * 16 + ocol;
      float bv_ = bias[c];
      #pragma unroll
      for (int j = 0; j < 4; ++j)
        Cout[(r0 + j) * (size_t)N + c] = acc[mi][ni][j] + bv_;
    }
  }
}

// ---------- launch ----------

extern "C" void kernel_launch(void* const* d_in, const int* in_sizes, int n_in,
                              void* d_out, int out_size, void* d_ws, size_t ws_size,
                              hipStream_t stream) {
  const float* x       = (const float*)d_in[0];   // [8192,4096]
  const float* q_w     = (const float*)d_in[1];   // [4096,4096]
  const float* q_b     = (const float*)d_in[2];   // [4096]
  const float* k_cache = (const float*)d_in[3];   // [100,4096]
  const float* v_cache = (const float*)d_in[4];   // [100,4096]
  const float* out_w   = (const float*)d_in[5];   // [4096,4096]
  const float* out_b   = (const float*)d_in[6];   // [4096]
  float* out = (float*)d_out;

  const int M = 8192, H = 4096;

  char* ws = (char*)d_ws;
  size_t off = 0;
  auto alloc = [&](size_t bytes) { void* p = ws + off; off += (bytes + 255) & ~(size_t)255; return p; };
  unsigned short* qwt2   = (unsigned short*)alloc((size_t)H * 8192 * 2);   // 67 MB
  unsigned short* kpad2  = (unsigned short*)alloc((size_t)128 * 8192 * 2); // 2 MB
  unsigned short* vpad   = (unsigned short*)alloc((size_t)128 * H * 2);    // 1 MB
  float*          sbias  = (float*)alloc(128 * 4);
  unsigned short* KQ2    = (unsigned short*)alloc((size_t)256 * H * 2);    // 2 MB
  unsigned short* W2     = (unsigned short*)alloc((size_t)M * 256 * 2);    // 4 MB
  unsigned short* VOT2   = (unsigned short*)alloc((size_t)H * 256 * 2);    // 2 MB
  float*          scratch= (float*)alloc((size_t)36 << 20);                // 36 MB
  if (ws_size < off) { fprintf(stderr, "ws too small: need %zu have %zu\n", off, ws_size); return; }

  // 1) preprocessing
  transpose_hilo<<<dim3(64, 64), 256, 0, stream>>>(q_w, qwt2);
  build_pad_dup<<<2048, 256, 0, stream>>>(k_cache, kpad2);
  build_pad128<<<2048, 256, 0, stream>>>(v_cache, vpad);
  kq_bias<<<128, 64, 0, stream>>>(k_cache, q_b, sbias);

  // 2) KQ = kpad @ q_w (via [kpad|kpad] @ [qwt_hi|qwt_lo]^T, K=8192), split-K 8
  gemm_ntk_splitk<<<dim3(8, 1, 32), 256, 0, stream>>>(kpad2, qwt2, scratch, 128, H, 8192, 1024);
  kq_reduce<<<2048, 256, 0, stream>>>(scratch, KQ2);

  // 3) S = x @ KQ2^T (hi/lo folded in-kernel, output width 128), pipelined, ksplit 8
  gemm_sv<256><<<dim3(8, 64), 256, 0, stream>>>(x, KQ2, scratch, M, H, 512);

  // 4) softmax -> W2 [8192][256] dup
  softmax_fused2<<<M / 4, 256, 0, stream>>>(scratch, sbias, W2, M);

  // 5) VO^T = out_w @ vpad^T, pipelined, ksplit 16
  gemm_sv<128><<<dim3(16, 32), 256, 0, stream>>>(out_w, vpad, scratch, H, H, 256);
  vo_reduce<<<2048, 256, 0, stream>>>(scratch, VOT2);

  // 6) out = W2 @ VOT2^T + out_b (K=256: [W|W] x [hi|lo])
  gemm_final<<<dim3(32, 64), 256, 0, stream>>>(W2, VOT2, out_b, out, M, H, 256);
}

// Round 13
// 188.360 us; speedup vs baseline: 1.1667x; 1.0697x over previous
//
#include <hip/hip_runtime.h>
#include <cstdio>

typedef __attribute__((ext_vector_type(8))) short short8;
typedef __attribute__((ext_vector_type(4))) float f32x4;

// ---------- helpers ----------

__device__ __forceinline__ unsigned short bf16r(float f) {
  union { float f; unsigned int u; } x; x.f = f;
  unsigned int r = x.u + 0x7fffu + ((x.u >> 16) & 1u);
  return (unsigned short)(r >> 16);
}

__device__ __forceinline__ float bf16f(unsigned short h) {
  union { unsigned int u; float f; } x; x.u = ((unsigned int)h) << 16;
  return x.f;
}

__device__ __forceinline__ void gload_lds16(const void* g, void* l) {
  __builtin_amdgcn_global_load_lds((const __attribute__((address_space(1))) void*)g,
                                   (__attribute__((address_space(3))) void*)l,
                                   16, 0, 0);
}

__device__ __forceinline__ short8 pack_bf16(float4 f0, float4 f1) {
  short8 h;
  h[0] = (short)bf16r(f0.x); h[1] = (short)bf16r(f0.y);
  h[2] = (short)bf16r(f0.z); h[3] = (short)bf16r(f0.w);
  h[4] = (short)bf16r(f1.x); h[5] = (short)bf16r(f1.y);
  h[6] = (short)bf16r(f1.z); h[7] = (short)bf16r(f1.w);
  return h;
}

// ---------- cache prep ----------

// src [100][4096] f32 -> dst [128][4096] bf16, rows>=100 zero (used for k and v)
__global__ void build_pad128(const float* __restrict__ src, unsigned short* __restrict__ dst) {
  int idx = blockIdx.x * blockDim.x + threadIdx.x;
  if (idx >= 128 * 4096) return;
  int row = idx >> 12;
  float v = (row < 100) ? src[idx] : 0.f;
  dst[idx] = bf16r(v);
}

__global__ void kq_bias(const float* __restrict__ kc, const float* __restrict__ qb,
                        float* __restrict__ sbias) {
  int l = blockIdx.x;
  int lane = threadIdx.x;
  float s = 0.f;
  if (l < 100) {
    for (int i = lane * 4; i < 4096; i += 256) {
      float4 k = *reinterpret_cast<const float4*>(kc + (size_t)l * 4096 + i);
      float4 q = *reinterpret_cast<const float4*>(qb + i);
      s += k.x * q.x + k.y * q.y + k.z * q.z + k.w * q.w;
    }
  }
  #pragma unroll
  for (int off = 1; off < 64; off <<= 1) s += __shfl_xor(s, off);
  if (lane == 0) sbias[l] = s;
}

// ---------- FUSED KQ GEMM: KQ[l][i] = sum_j kpad[l][j] * q_w[j][i], hi/lo in-kernel ----------
// Streams q_w f32 ONCE (no qwt2 materialization). A = kpad (L2, gload_lds m97 staging),
// B = q_w transposed through +1-padded f32 LDS tile Ts[32][129] (conflict-managed),
// hi/lo bf16 split at frag read, 2 MFMAs (hi+lo) into one f32 acc — numerics identical
// to the old qwt2 path. grid (jsplit=8, itiles=32); Cpart[js][128][4096].

__global__ __launch_bounds__(256)
void kq_fused(const unsigned short* __restrict__ Kp,   // kpad [128][4096] bf16
              const float* __restrict__ Qw,            // q_w  [4096][4096] f32
              float* __restrict__ Cpart,
              int H, int jchunk) {
  __shared__ unsigned short Ak[128][32];   // 8 KB
  __shared__ float Ts[32][129];            // 16.5 KB

  const int tid = threadIdx.x, wave = tid >> 6, lane = tid & 63;
  const int wm = wave >> 1, wn = wave & 1;
  const int j0 = blockIdx.x * jchunk;
  const int i0 = blockIdx.y * 128;

  // kpad staging (m97 linear): rows sr / sr+64, 16B per lane
  const int sr = wave * 16 + (lane >> 2);
  const int sc = (lane & 3) << 3;
  const unsigned short* Kp0 = Kp + (size_t)sr * H + j0 + sc;
  const unsigned short* Kp1 = Kp + (size_t)(64 + sr) * H + j0 + sc;
  unsigned short* AD0 = &Ak[wave * 16][0];
  unsigned short* AD1 = &Ak[64 + wave * 16][0];

  // q_w staging: thread t -> row j=t>>3, cols (t&7)*16 .. +15 (4x float4, coalesced)
  const int tj = tid >> 3;
  const int tc = (tid & 7) * 16;
  const float* Qp = Qw + (size_t)(j0 + tj) * H + i0 + tc;

  const int fr = lane & 15;
  const int kq = lane >> 4;

  f32x4 acc[4][4] = {};

  for (int jj = 0; jj < jchunk; jj += 32) {
    gload_lds16(Kp0 + jj, AD0);
    gload_lds16(Kp1 + jj, AD1);
    {
      const float* q = Qp + (size_t)jj * H;
      float4 v0 = *reinterpret_cast<const float4*>(q);
      float4 v1 = *reinterpret_cast<const float4*>(q + 4);
      float4 v2 = *reinterpret_cast<const float4*>(q + 8);
      float4 v3 = *reinterpret_cast<const float4*>(q + 12);
      Ts[tj][tc + 0]  = v0.x; Ts[tj][tc + 1]  = v0.y; Ts[tj][tc + 2]  = v0.z; Ts[tj][tc + 3]  = v0.w;
      Ts[tj][tc + 4]  = v1.x; Ts[tj][tc + 5]  = v1.y; Ts[tj][tc + 6]  = v1.z; Ts[tj][tc + 7]  = v1.w;
      Ts[tj][tc + 8]  = v2.x; Ts[tj][tc + 9]  = v2.y; Ts[tj][tc + 10] = v2.z; Ts[tj][tc + 11] = v2.w;
      Ts[tj][tc + 12] = v3.x; Ts[tj][tc + 13] = v3.y; Ts[tj][tc + 14] = v3.z; Ts[tj][tc + 15] = v3.w;
    }
    __syncthreads();

    short8 av[4];
    #pragma unroll
    for (int mi = 0; mi < 4; ++mi)
      av[mi] = *reinterpret_cast<const short8*>(&Ak[wm * 64 + mi * 16 + fr][kq * 8]);

    short8 bhi[4], blo[4];
    #pragma unroll
    for (int ni = 0; ni < 4; ++ni) {
      const int ic = wn * 64 + ni * 16 + fr;
      #pragma unroll
      for (int s = 0; s < 8; ++s) {
        float f = Ts[kq * 8 + s][ic];           // column read; 129 = +1 pad -> ~2-way
        unsigned short h = bf16r(f);
        bhi[ni][s] = (short)h;
        blo[ni][s] = (short)bf16r(f - bf16f(h));
      }
    }

    #pragma unroll
    for (int mi = 0; mi < 4; ++mi)
      #pragma unroll
      for (int ni = 0; ni < 4; ++ni) {
        acc[mi][ni] = __builtin_amdgcn_mfma_f32_16x16x32_bf16(av[mi], bhi[ni], acc[mi][ni], 0, 0, 0);
        acc[mi][ni] = __builtin_amdgcn_mfma_f32_16x16x32_bf16(av[mi], blo[ni], acc[mi][ni], 0, 0, 0);
      }
    __syncthreads();
  }

  float* Cp = Cpart + (size_t)blockIdx.x * 128 * H;
  const int orow = (lane >> 4) * 4;
  const int ocol = lane & 15;
  #pragma unroll
  for (int mi = 0; mi < 4; ++mi) {
    #pragma unroll
    for (int ni = 0; ni < 4; ++ni) {
      size_t r0 = (size_t)wm * 64 + mi * 16 + orow;
      size_t c  = (size_t)i0 + wn * 64 + ni * 16 + ocol;
      #pragma unroll
      for (int j = 0; j < 4; ++j)
        Cp[(r0 + j) * (size_t)H + c] = acc[mi][ni][j];
    }
  }
}

// ---------- PIPELINED streaming GEMM (counted-vmcnt, r12-proven) ----------

template<int NB>
__global__ __launch_bounds__(256, 1)
void gemm_sv(const float* __restrict__ A, const unsigned short* __restrict__ B,
             float* __restrict__ Cpart, int M, int Kstride, int kchunk) {
  constexpr int FOLD = NB / 128;
  __shared__ float          As[2][128][32];
  __shared__ unsigned short Bs[2][NB][32];

  const int tid = threadIdx.x, wave = tid >> 6, lane = tid & 63;
  const int wm = wave >> 1, wn = wave & 1;
  const int ks = blockIdx.x, mblk = blockIdx.y;
  const size_t rowA0 = (size_t)mblk * 128;
  const int k0 = ks * kchunk;
  const int nsteps = kchunk >> 5;

  const int ar = lane >> 3;
  const int as_g = (lane & 7) ^ ar;
  const int br = lane >> 2;
  const int bs_g = (lane & 3) ^ (br & 3);

#define STAGE_SV(kt, BUF) do { \
    const int _kc = k0 + (kt) * 32; \
    _Pragma("unroll") \
    for (int j = 0; j < 4; ++j) \
      gload_lds16(A + (rowA0 + wave * 32 + j * 8 + ar) * (size_t)Kstride + _kc + as_g * 4, \
                  &As[BUF][wave * 32 + j * 8][0]); \
    _Pragma("unroll") \
    for (int j = 0; j < NB / 64; ++j) \
      gload_lds16(B + (size_t)(wave * (NB / 4) + j * 16 + br) * Kstride + _kc + bs_g * 8, \
                  &Bs[BUF][wave * (NB / 4) + j * 16][0]); \
  } while (0)

#define WAIT_STAGE do { \
    if (NB == 256) asm volatile("s_waitcnt vmcnt(8)" ::: "memory"); \
    else           asm volatile("s_waitcnt vmcnt(6)" ::: "memory"); \
  } while (0)

  const int fr = lane & 15, kq = lane >> 4;
  f32x4 acc[4][4] = {};

  STAGE_SV(0, 0);
  STAGE_SV(1, 1);
  WAIT_STAGE;
  asm volatile("" ::: "memory");
  __builtin_amdgcn_s_barrier();
  asm volatile("" ::: "memory");

  for (int k = 0; k < nsteps; ++k) {
    const int c = k & 1;

    short8 av[4], bv[4][FOLD];
    #pragma unroll
    for (int mi = 0; mi < 4; ++mi) {
      const float* rp = &As[c][wm * 64 + mi * 16 + fr][0];
      float4 f0 = *reinterpret_cast<const float4*>(rp + (((2 * kq)     ^ (fr & 7)) * 4));
      float4 f1 = *reinterpret_cast<const float4*>(rp + (((2 * kq + 1) ^ (fr & 7)) * 4));
      av[mi] = pack_bf16(f0, f1);
    }
    #pragma unroll
    for (int ni = 0; ni < 4; ++ni)
      #pragma unroll
      for (int p = 0; p < FOLD; ++p) {
        int rb = p * 128 + wn * 64 + ni * 16 + fr;
        bv[ni][p] = *reinterpret_cast<const short8*>(&Bs[c][rb][0] + ((kq ^ (fr & 3)) * 8));
      }

    asm volatile("s_waitcnt lgkmcnt(0)" ::: "memory");
    __builtin_amdgcn_s_barrier();
    asm volatile("" ::: "memory");

    const int kt2 = (k + 2 < nsteps) ? k + 2 : nsteps - 1;
    STAGE_SV(kt2, c);
    asm volatile("" ::: "memory");

    __builtin_amdgcn_s_setprio(1);
    #pragma unroll
    for (int mi = 0; mi < 4; ++mi)
      #pragma unroll
      for (int ni = 0; ni < 4; ++ni)
        #pragma unroll
        for (int p = 0; p < FOLD; ++p)
          acc[mi][ni] = __builtin_amdgcn_mfma_f32_16x16x32_bf16(av[mi], bv[ni][p], acc[mi][ni], 0, 0, 0);
    __builtin_amdgcn_s_setprio(0);

    WAIT_STAGE;
    asm volatile("" ::: "memory");
    __builtin_amdgcn_s_barrier();
    asm volatile("" ::: "memory");
  }

#undef STAGE_SV
#undef WAIT_STAGE

  float* Cp = Cpart + (size_t)ks * M * 128;
  const int orow = (lane >> 4) * 4;
  const int ocol = lane & 15;
  #pragma unroll
  for (int mi = 0; mi < 4; ++mi) {
    #pragma unroll
    for (int ni = 0; ni < 4; ++ni) {
      size_t r0 = rowA0 + wm * 64 + mi * 16 + orow;
      size_t c  = (size_t)wn * 64 + ni * 16 + ocol;
      #pragma unroll
      for (int j = 0; j < 4; ++j)
        Cp[(r0 + j) * 128 + c] = acc[mi][ni][j];
    }
  }
}

// ---------- KQ reduce (8 partials [128][4096] -> KQ2 [256][4096] hi|lo) ----------

__global__ void kq_reduce(const float* __restrict__ KQpart, unsigned short* __restrict__ KQ2) {
  int idx = blockIdx.x * blockDim.x + threadIdx.x;
  if (idx >= 128 * 4096) return;
  float s = 0.f;
  #pragma unroll
  for (int ks = 0; ks < 8; ++ks) s += KQpart[(size_t)ks * 128 * 4096 + idx];
  unsigned short hi = bf16r(s);
  unsigned short lo = bf16r(s - bf16f(hi));
  int l = idx >> 12, j = idx & 4095;
  KQ2[(size_t)l * 4096 + j]         = hi;
  KQ2[(size_t)(l + 128) * 4096 + j] = lo;
}

// ---------- softmax: sum 8 ks-partials (width 128) + bias -> [W|W] bf16 [rows][256] ----------

__global__ void softmax_fused2(const float* __restrict__ Spart, const float* __restrict__ sbias,
                               unsigned short* __restrict__ W2, int rows) {
  int wave = threadIdx.x >> 6;
  int lane = threadIdx.x & 63;
  int row = blockIdx.x * (blockDim.x >> 6) + wave;
  if (row >= rows) return;
  const float scale = 0.088388347648318447f;
  float sx = 0.f, sy = 0.f;
  #pragma unroll
  for (int ks = 0; ks < 8; ++ks) {
    float2 p = reinterpret_cast<const float2*>(Spart + ((size_t)ks * rows + row) * 128)[lane];
    sx += p.x; sy += p.y;
  }
  float2 bb = reinterpret_cast<const float2*>(sbias)[lane];
  sx += bb.x; sy += bb.y;
  int c0 = lane * 2, c1 = c0 + 1;
  float s0 = (c0 <= 100) ? sx * scale : -1e30f;
  float s1 = (c1 <= 100) ? sy * scale : -1e30f;
  float m = fmaxf(s0, s1);
  #pragma unroll
  for (int off = 1; off < 64; off <<= 1) m = fmaxf(m, __shfl_xor(m, off));
  float e0 = (c0 <= 100) ? __expf(s0 - m) : 0.f;
  float e1 = (c1 <= 100) ? __expf(s1 - m) : 0.f;
  float sum = e0 + e1;
  #pragma unroll
  for (int off = 1; off < 64; off <<= 1) sum += __shfl_xor(sum, off);
  float inv = 1.f / sum;
  ushort2 o;
  o.x = bf16r(e0 * inv);
  o.y = bf16r(e1 * inv);
  reinterpret_cast<ushort2*>(W2 + (size_t)row * 256)[lane] = o;
  reinterpret_cast<ushort2*>(W2 + (size_t)row * 256 + 128)[lane] = o;
}

// ---------- VO reduce (16 partials) ----------

__global__ void vo_reduce(const float* __restrict__ VOpart, unsigned short* __restrict__ VOT2) {
  int idx = blockIdx.x * blockDim.x + threadIdx.x;
  if (idx >= 4096 * 128) return;
  float s = 0.f;
  #pragma unroll
  for (int ks = 0; ks < 16; ++ks) s += VOpart[(size_t)ks * 4096 * 128 + idx];
  unsigned short hi = bf16r(s);
  unsigned short lo = bf16r(s - bf16f(hi));
  int o = idx >> 7, l = idx & 127;
  VOT2[(size_t)o * 256 + l]       = hi;
  VOT2[(size_t)o * 256 + 128 + l] = lo;
}

// ---------- padded-LDS reg-staged GEMM (final: out = W2 @ VOT2^T + out_b) ----------

__global__ __launch_bounds__(256)
void gemm_final(const unsigned short* __restrict__ A,
                const unsigned short* __restrict__ B,
                const float* __restrict__ bias,
                float* __restrict__ Cout,
                int M, int N, int K) {
  __shared__ unsigned short As[128][40];
  __shared__ unsigned short Bs[128][40];

  const int tid = threadIdx.x, wave = tid >> 6, lane = tid & 63;
  const int wm = wave >> 1, wn = wave & 1;
  const size_t rowA0 = (size_t)blockIdx.y * 128;
  const size_t colB0 = (size_t)blockIdx.x * 128;

  f32x4 acc[4][4] = {};

  const int srow  = tid >> 1;
  const int shalf = (tid & 1) * 16;

  const unsigned short* Ap = A + (rowA0 + srow) * (size_t)K + shalf;
  const unsigned short* Bp = B + (colB0 + srow) * (size_t)K + shalf;

  const int fr = lane & 15;
  const int fk = (lane >> 4) << 3;

  for (int k0 = 0; k0 < K; k0 += 32) {
    short8 a0 = *reinterpret_cast<const short8*>(Ap + k0);
    short8 a1 = *reinterpret_cast<const short8*>(Ap + k0 + 8);
    short8 b0 = *reinterpret_cast<const short8*>(Bp + k0);
    short8 b1 = *reinterpret_cast<const short8*>(Bp + k0 + 8);
    *reinterpret_cast<short8*>(&As[srow][shalf])     = a0;
    *reinterpret_cast<short8*>(&As[srow][shalf + 8]) = a1;
    *reinterpret_cast<short8*>(&Bs[srow][shalf])     = b0;
    *reinterpret_cast<short8*>(&Bs[srow][shalf + 8]) = b1;
    __syncthreads();

    short8 av[4], bv[4];
    #pragma unroll
    for (int mi = 0; mi < 4; ++mi)
      av[mi] = *reinterpret_cast<const short8*>(&As[wm * 64 + mi * 16 + fr][fk]);
    #pragma unroll
    for (int ni = 0; ni < 4; ++ni)
      bv[ni] = *reinterpret_cast<const short8*>(&Bs[wn * 64 + ni * 16 + fr][fk]);
    #pragma unroll
    for (int mi = 0; mi < 4; ++mi)
      #pragma unroll
      for (int ni = 0; ni < 4; ++ni)
        acc[mi][ni] = __builtin_amdgcn_mfma_f32_16x16x32_bf16(av[mi], bv[ni], acc[mi][ni], 0, 0, 0);
    __syncthreads();
  }

  const int orow = (lane >> 4) * 4;
  const int ocol = lane & 15;
  #pragma unroll
  for (int mi = 0; mi < 4; ++mi) {
    #pragma unroll
    for (int ni = 0; ni < 4; ++ni) {
      size_t r0 = rowA0 + wm * 64 + mi * 16 + orow;
      size_t c  = colB0 + wn * 64 + ni * 16 + ocol;
      float bv_ = bias[c];
      #pragma unroll
      for (int j = 0; j < 4; ++j)
        Cout[(r0 + j) * (size_t)N + c] = acc[mi][ni][j] + bv_;
    }
  }
}

// ---------- launch ----------

extern "C" void kernel_launch(void* const* d_in, const int* in_sizes, int n_in,
                              void* d_out, int out_size, void* d_ws, size_t ws_size,
                              hipStream_t stream) {
  const float* x       = (const float*)d_in[0];   // [8192,4096]
  const float* q_w     = (const float*)d_in[1];   // [4096,4096]
  const float* q_b     = (const float*)d_in[2];   // [4096]
  const float* k_cache = (const float*)d_in[3];   // [100,4096]
  const float* v_cache = (const float*)d_in[4];   // [100,4096]
  const float* out_w   = (const float*)d_in[5];   // [4096,4096]
  const float* out_b   = (const float*)d_in[6];   // [4096]
  float* out = (float*)d_out;

  const int M = 8192, H = 4096;

  char* ws = (char*)d_ws;
  size_t off = 0;
  auto alloc = [&](size_t bytes) { void* p = ws + off; off += (bytes + 255) & ~(size_t)255; return p; };
  unsigned short* kpad   = (unsigned short*)alloc((size_t)128 * H * 2);    // 1 MB
  unsigned short* vpad   = (unsigned short*)alloc((size_t)128 * H * 2);    // 1 MB
  float*          sbias  = (float*)alloc(128 * 4);
  unsigned short* KQ2    = (unsigned short*)alloc((size_t)256 * H * 2);    // 2 MB
  unsigned short* W2     = (unsigned short*)alloc((size_t)M * 256 * 2);    // 4 MB
  unsigned short* VOT2   = (unsigned short*)alloc((size_t)H * 256 * 2);    // 2 MB
  float*          scratch= (float*)alloc((size_t)36 << 20);                // 36 MB
  if (ws_size < off) { fprintf(stderr, "ws too small: need %zu have %zu\n", off, ws_size); return; }

  // 1) preprocessing (no q_w transpose pass anymore)
  build_pad128<<<2048, 256, 0, stream>>>(k_cache, kpad);
  build_pad128<<<2048, 256, 0, stream>>>(v_cache, vpad);
  kq_bias<<<128, 64, 0, stream>>>(k_cache, q_b, sbias);

  // 2) KQ = kpad @ q_w, FUSED transpose + hi/lo, jsplit 8 -> 256 blocks
  kq_fused<<<dim3(8, 32), 256, 0, stream>>>(kpad, q_w, scratch, H, 512);
  kq_reduce<<<2048, 256, 0, stream>>>(scratch, KQ2);

  // 3) S = x @ KQ2^T (hi/lo folded in-kernel, output width 128), pipelined, ksplit 8
  gemm_sv<256><<<dim3(8, 64), 256, 0, stream>>>(x, KQ2, scratch, M, H, 512);

  // 4) softmax -> W2 [8192][256] dup
  softmax_fused2<<<M / 4, 256, 0, stream>>>(scratch, sbias, W2, M);

  // 5) VO^T = out_w @ vpad^T, pipelined, ksplit 16
  gemm_sv<128><<<dim3(16, 32), 256, 0, stream>>>(out_w, vpad, scratch, H, H, 256);
  vo_reduce<<<2048, 256, 0, stream>>>(scratch, VOT2);

  // 6) out = W2 @ VOT2^T + out_b (K=256: [W|W] x [hi|lo])
  gemm_final<<<dim3(32, 64), 256, 0, stream>>>(W2, VOT2, out_b, out, M, H, 256);
}

// Round 14
// 161.891 us; speedup vs baseline: 1.3575x; 1.1635x over previous
//
#include <hip/hip_runtime.h>
#include <cstdio>

typedef __attribute__((ext_vector_type(8))) short short8;
typedef __attribute__((ext_vector_type(4))) float f32x4;

// ---------- helpers ----------

__device__ __forceinline__ unsigned short bf16r(float f) {
  union { float f; unsigned int u; } x; x.f = f;
  unsigned int r = x.u + 0x7fffu + ((x.u >> 16) & 1u);
  return (unsigned short)(r >> 16);
}

__device__ __forceinline__ float bf16f(unsigned short h) {
  union { unsigned int u; float f; } x; x.u = ((unsigned int)h) << 16;
  return x.f;
}

__device__ __forceinline__ void gload_lds16(const void* g, void* l) {
  __builtin_amdgcn_global_load_lds((const __attribute__((address_space(1))) void*)g,
                                   (__attribute__((address_space(3))) void*)l,
                                   16, 0, 0);
}

__device__ __forceinline__ short8 pack_bf16(float4 f0, float4 f1) {
  short8 h;
  h[0] = (short)bf16r(f0.x); h[1] = (short)bf16r(f0.y);
  h[2] = (short)bf16r(f0.z); h[3] = (short)bf16r(f0.w);
  h[4] = (short)bf16r(f1.x); h[5] = (short)bf16r(f1.y);
  h[6] = (short)bf16r(f1.z); h[7] = (short)bf16r(f1.w);
  return h;
}

// ---------- prep: kpad, vpad, sbias in ONE launch ----------
// blocks [0,2048): kpad; [2048,4096): vpad; [4096,4128): kq_bias (wave per l).

__global__ void prep(const float* __restrict__ kc, const float* __restrict__ vc,
                     const float* __restrict__ qb,
                     unsigned short* __restrict__ kpad, unsigned short* __restrict__ vpad,
                     float* __restrict__ sbias) {
  const int b = blockIdx.x, tid = threadIdx.x;
  if (b < 4096) {
    const bool isK = b < 2048;
    const int bb = isK ? b : b - 2048;
    int idx = bb * 256 + tid;                 // over 128*4096
    int row = idx >> 12;
    const float* src = isK ? kc : vc;
    float v = (row < 100) ? src[idx] : 0.f;
    (isK ? kpad : vpad)[idx] = bf16r(v);
  } else {
    const int wave = tid >> 6, lane = tid & 63;
    const int l = (b - 4096) * 4 + wave;      // 0..127
    float s = 0.f;
    if (l < 100) {
      for (int i = lane * 4; i < 4096; i += 256) {
        float4 k = *reinterpret_cast<const float4*>(kc + (size_t)l * 4096 + i);
        float4 q = *reinterpret_cast<const float4*>(qb + i);
        s += k.x * q.x + k.y * q.y + k.z * q.z + k.w * q.w;
      }
    }
    #pragma unroll
    for (int off = 1; off < 64; off <<= 1) s += __shfl_xor(s, off);
    if (lane == 0) sbias[l] = s;
  }
}

// ---------- kq_fused body (r13-proven) ----------
// smem layout: Ak [128][32] u16 @0 (8 KB); Ts [32][129] f32 @8192 (16.5 KB).

__device__ __forceinline__ void kq_fused_body(const unsigned short* __restrict__ Kp,
                                              const float* __restrict__ Qw,
                                              float* __restrict__ Cpart,
                                              int H, int jchunk, int js, int itile,
                                              char* smem) {
  unsigned short (*Ak)[32] = (unsigned short (*)[32])smem;
  float (*Ts)[129] = (float (*)[129])(smem + 8192);

  const int tid = threadIdx.x, wave = tid >> 6, lane = tid & 63;
  const int wm = wave >> 1, wn = wave & 1;
  const int j0 = js * jchunk;
  const int i0 = itile * 128;

  const int sr = wave * 16 + (lane >> 2);
  const int sc = (lane & 3) << 3;
  const unsigned short* Kp0 = Kp + (size_t)sr * H + j0 + sc;
  const unsigned short* Kp1 = Kp + (size_t)(64 + sr) * H + j0 + sc;
  unsigned short* AD0 = &Ak[wave * 16][0];
  unsigned short* AD1 = &Ak[64 + wave * 16][0];

  const int tj = tid >> 3;
  const int tc = (tid & 7) * 16;
  const float* Qp = Qw + (size_t)(j0 + tj) * H + i0 + tc;

  const int fr = lane & 15;
  const int kq = lane >> 4;

  f32x4 acc[4][4] = {};

  for (int jj = 0; jj < jchunk; jj += 32) {
    gload_lds16(Kp0 + jj, AD0);
    gload_lds16(Kp1 + jj, AD1);
    {
      const float* q = Qp + (size_t)jj * H;
      float4 v0 = *reinterpret_cast<const float4*>(q);
      float4 v1 = *reinterpret_cast<const float4*>(q + 4);
      float4 v2 = *reinterpret_cast<const float4*>(q + 8);
      float4 v3 = *reinterpret_cast<const float4*>(q + 12);
      Ts[tj][tc + 0]  = v0.x; Ts[tj][tc + 1]  = v0.y; Ts[tj][tc + 2]  = v0.z; Ts[tj][tc + 3]  = v0.w;
      Ts[tj][tc + 4]  = v1.x; Ts[tj][tc + 5]  = v1.y; Ts[tj][tc + 6]  = v1.z; Ts[tj][tc + 7]  = v1.w;
      Ts[tj][tc + 8]  = v2.x; Ts[tj][tc + 9]  = v2.y; Ts[tj][tc + 10] = v2.z; Ts[tj][tc + 11] = v2.w;
      Ts[tj][tc + 12] = v3.x; Ts[tj][tc + 13] = v3.y; Ts[tj][tc + 14] = v3.z; Ts[tj][tc + 15] = v3.w;
    }
    __syncthreads();

    short8 av[4];
    #pragma unroll
    for (int mi = 0; mi < 4; ++mi)
      av[mi] = *reinterpret_cast<const short8*>(&Ak[wm * 64 + mi * 16 + fr][kq * 8]);

    short8 bhi[4], blo[4];
    #pragma unroll
    for (int ni = 0; ni < 4; ++ni) {
      const int ic = wn * 64 + ni * 16 + fr;
      #pragma unroll
      for (int s = 0; s < 8; ++s) {
        float f = Ts[kq * 8 + s][ic];
        unsigned short h = bf16r(f);
        bhi[ni][s] = (short)h;
        blo[ni][s] = (short)bf16r(f - bf16f(h));
      }
    }

    #pragma unroll
    for (int mi = 0; mi < 4; ++mi)
      #pragma unroll
      for (int ni = 0; ni < 4; ++ni) {
        acc[mi][ni] = __builtin_amdgcn_mfma_f32_16x16x32_bf16(av[mi], bhi[ni], acc[mi][ni], 0, 0, 0);
        acc[mi][ni] = __builtin_amdgcn_mfma_f32_16x16x32_bf16(av[mi], blo[ni], acc[mi][ni], 0, 0, 0);
      }
    __syncthreads();
  }

  float* Cp = Cpart + (size_t)js * 128 * H;
  const int orow = (lane >> 4) * 4;
  const int ocol = lane & 15;
  #pragma unroll
  for (int mi = 0; mi < 4; ++mi) {
    #pragma unroll
    for (int ni = 0; ni < 4; ++ni) {
      size_t r0 = (size_t)wm * 64 + mi * 16 + orow;
      size_t c  = (size_t)i0 + wn * 64 + ni * 16 + ocol;
      #pragma unroll
      for (int j = 0; j < 4; ++j)
        Cp[(r0 + j) * (size_t)H + c] = acc[mi][ni][j];
    }
  }
}

// ---------- gemm_sv body (r12-proven counted-vmcnt pipeline) ----------
// smem layout: As [2][128][32] f32 @0 (32 KB); Bs [2][NB][32] u16 @32768.

template<int NB>
__device__ __forceinline__ void gemm_sv_body(const float* __restrict__ A,
                                             const unsigned short* __restrict__ B,
                                             float* __restrict__ Cpart,
                                             int M, int Kstride, int kchunk,
                                             int ks, int mblk, char* smem) {
  constexpr int FOLD = NB / 128;
  float (*As)[128][32] = (float (*)[128][32])smem;
  unsigned short (*Bs)[NB][32] = (unsigned short (*)[NB][32])(smem + 32768);

  const int tid = threadIdx.x, wave = tid >> 6, lane = tid & 63;
  const int wm = wave >> 1, wn = wave & 1;
  const size_t rowA0 = (size_t)mblk * 128;
  const int k0 = ks * kchunk;
  const int nsteps = kchunk >> 5;

  const int ar = lane >> 3;
  const int as_g = (lane & 7) ^ ar;
  const int br = lane >> 2;
  const int bs_g = (lane & 3) ^ (br & 3);

#define STAGE_SV(kt, BUF) do { \
    const int _kc = k0 + (kt) * 32; \
    _Pragma("unroll") \
    for (int j = 0; j < 4; ++j) \
      gload_lds16(A + (rowA0 + wave * 32 + j * 8 + ar) * (size_t)Kstride + _kc + as_g * 4, \
                  &As[BUF][wave * 32 + j * 8][0]); \
    _Pragma("unroll") \
    for (int j = 0; j < NB / 64; ++j) \
      gload_lds16(B + (size_t)(wave * (NB / 4) + j * 16 + br) * Kstride + _kc + bs_g * 8, \
                  &Bs[BUF][wave * (NB / 4) + j * 16][0]); \
  } while (0)

#define WAIT_STAGE do { \
    if (NB == 256) asm volatile("s_waitcnt vmcnt(8)" ::: "memory"); \
    else           asm volatile("s_waitcnt vmcnt(6)" ::: "memory"); \
  } while (0)

  const int fr = lane & 15, kq = lane >> 4;
  f32x4 acc[4][4] = {};

  STAGE_SV(0, 0);
  STAGE_SV(1, 1);
  WAIT_STAGE;
  asm volatile("" ::: "memory");
  __builtin_amdgcn_s_barrier();
  asm volatile("" ::: "memory");

  for (int k = 0; k < nsteps; ++k) {
    const int c = k & 1;

    short8 av[4], bv[4][FOLD];
    #pragma unroll
    for (int mi = 0; mi < 4; ++mi) {
      const float* rp = &As[c][wm * 64 + mi * 16 + fr][0];
      float4 f0 = *reinterpret_cast<const float4*>(rp + (((2 * kq)     ^ (fr & 7)) * 4));
      float4 f1 = *reinterpret_cast<const float4*>(rp + (((2 * kq + 1) ^ (fr & 7)) * 4));
      av[mi] = pack_bf16(f0, f1);
    }
    #pragma unroll
    for (int ni = 0; ni < 4; ++ni)
      #pragma unroll
      for (int p = 0; p < FOLD; ++p) {
        int rb = p * 128 + wn * 64 + ni * 16 + fr;
        bv[ni][p] = *reinterpret_cast<const short8*>(&Bs[c][rb][0] + ((kq ^ (fr & 3)) * 8));
      }

    asm volatile("s_waitcnt lgkmcnt(0)" ::: "memory");
    __builtin_amdgcn_s_barrier();
    asm volatile("" ::: "memory");

    const int kt2 = (k + 2 < nsteps) ? k + 2 : nsteps - 1;
    STAGE_SV(kt2, c);
    asm volatile("" ::: "memory");

    __builtin_amdgcn_s_setprio(1);
    #pragma unroll
    for (int mi = 0; mi < 4; ++mi)
      #pragma unroll
      for (int ni = 0; ni < 4; ++ni)
        #pragma unroll
        for (int p = 0; p < FOLD; ++p)
          acc[mi][ni] = __builtin_amdgcn_mfma_f32_16x16x32_bf16(av[mi], bv[ni][p], acc[mi][ni], 0, 0, 0);
    __builtin_amdgcn_s_setprio(0);

    WAIT_STAGE;
    asm volatile("" ::: "memory");
    __builtin_amdgcn_s_barrier();
    asm volatile("" ::: "memory");
  }

#undef STAGE_SV
#undef WAIT_STAGE

  float* Cp = Cpart + (size_t)ks * M * 128;
  const int orow = (lane >> 4) * 4;
  const int ocol = lane & 15;
  #pragma unroll
  for (int mi = 0; mi < 4; ++mi) {
    #pragma unroll
    for (int ni = 0; ni < 4; ++ni) {
      size_t r0 = rowA0 + wm * 64 + mi * 16 + orow;
      size_t c  = (size_t)wn * 64 + ni * 16 + ocol;
      #pragma unroll
      for (int j = 0; j < 4; ++j)
        Cp[(r0 + j) * 128 + c] = acc[mi][ni][j];
    }
  }
}

// ---------- super-kernel: KQ GEMM (blocks 0..255) || VO GEMM (blocks 256..767) ----------

__global__ __launch_bounds__(256, 1)
void fused_kqvo(const unsigned short* __restrict__ kpad, const float* __restrict__ qw,
                float* __restrict__ KQpart,
                const float* __restrict__ outw, const unsigned short* __restrict__ vpad,
                float* __restrict__ VOpart, int H) {
  __shared__ __align__(16) char smem[49152];
  const int b = blockIdx.x;
  if (b < 256) {
    kq_fused_body(kpad, qw, KQpart, H, 512, b & 7, b >> 3, smem);
  } else {
    const int b2 = b - 256;
    gemm_sv_body<128>(outw, vpad, VOpart, H, H, 256, b2 & 15, b2 >> 4, smem);
  }
}

// ---------- standalone S GEMM ----------

__global__ __launch_bounds__(256, 1)
void gemm_s(const float* __restrict__ A, const unsigned short* __restrict__ B,
            float* __restrict__ Cpart, int M, int Kstride, int kchunk) {
  __shared__ __align__(16) char smem[65536];
  gemm_sv_body<256>(A, B, Cpart, M, Kstride, kchunk, blockIdx.x, blockIdx.y, smem);
}

// ---------- merged reduces: kq_reduce (blocks 0..2047) || vo_reduce (2048..4095) ----------

__global__ void reduces(const float* __restrict__ KQpart, unsigned short* __restrict__ KQ2,
                        const float* __restrict__ VOpart, unsigned short* __restrict__ VOT2) {
  const int b = blockIdx.x;
  if (b < 2048) {
    int idx = b * 256 + threadIdx.x;          // over 128*4096, idx = l*4096 + j
    float s = 0.f;
    #pragma unroll
    for (int ks = 0; ks < 8; ++ks) s += KQpart[(size_t)ks * 128 * 4096 + idx];
    unsigned short hi = bf16r(s);
    unsigned short lo = bf16r(s - bf16f(hi));
    int l = idx >> 12, j = idx & 4095;
    KQ2[(size_t)l * 4096 + j]         = hi;
    KQ2[(size_t)(l + 128) * 4096 + j] = lo;
  } else {
    int idx = (b - 2048) * 256 + threadIdx.x; // over 4096*128, idx = o*128 + l
    float s = 0.f;
    #pragma unroll
    for (int ks = 0; ks < 16; ++ks) s += VOpart[(size_t)ks * 4096 * 128 + idx];
    unsigned short hi = bf16r(s);
    unsigned short lo = bf16r(s - bf16f(hi));
    int o = idx >> 7, l = idx & 127;
    VOT2[(size_t)o * 256 + l]       = hi;
    VOT2[(size_t)o * 256 + 128 + l] = lo;
  }
}

// ---------- softmax: sum 8 ks-partials (width 128) + bias -> [W|W] bf16 [rows][256] ----------

__global__ void softmax_fused2(const float* __restrict__ Spart, const float* __restrict__ sbias,
                               unsigned short* __restrict__ W2, int rows) {
  int wave = threadIdx.x >> 6;
  int lane = threadIdx.x & 63;
  int row = blockIdx.x * (blockDim.x >> 6) + wave;
  if (row >= rows) return;
  const float scale = 0.088388347648318447f;
  float sx = 0.f, sy = 0.f;
  #pragma unroll
  for (int ks = 0; ks < 8; ++ks) {
    float2 p = reinterpret_cast<const float2*>(Spart + ((size_t)ks * rows + row) * 128)[lane];
    sx += p.x; sy += p.y;
  }
  float2 bb = reinterpret_cast<const float2*>(sbias)[lane];
  sx += bb.x; sy += bb.y;
  int c0 = lane * 2, c1 = c0 + 1;
  float s0 = (c0 <= 100) ? sx * scale : -1e30f;
  float s1 = (c1 <= 100) ? sy * scale : -1e30f;
  float m = fmaxf(s0, s1);
  #pragma unroll
  for (int off = 1; off < 64; off <<= 1) m = fmaxf(m, __shfl_xor(m, off));
  float e0 = (c0 <= 100) ? __expf(s0 - m) : 0.f;
  float e1 = (c1 <= 100) ? __expf(s1 - m) : 0.f;
  float sum = e0 + e1;
  #pragma unroll
  for (int off = 1; off < 64; off <<= 1) sum += __shfl_xor(sum, off);
  float inv = 1.f / sum;
  ushort2 o;
  o.x = bf16r(e0 * inv);
  o.y = bf16r(e1 * inv);
  reinterpret_cast<ushort2*>(W2 + (size_t)row * 256)[lane] = o;
  reinterpret_cast<ushort2*>(W2 + (size_t)row * 256 + 128)[lane] = o;
}

// ---------- padded-LDS reg-staged GEMM (final: out = W2 @ VOT2^T + out_b) ----------

__global__ __launch_bounds__(256)
void gemm_final(const unsigned short* __restrict__ A,
                const unsigned short* __restrict__ B,
                const float* __restrict__ bias,
                float* __restrict__ Cout,
                int M, int N, int K) {
  __shared__ unsigned short As[128][40];
  __shared__ unsigned short Bs[128][40];

  const int tid = threadIdx.x, wave = tid >> 6, lane = tid & 63;
  const int wm = wave >> 1, wn = wave & 1;
  const size_t rowA0 = (size_t)blockIdx.y * 128;
  const size_t colB0 = (size_t)blockIdx.x * 128;

  f32x4 acc[4][4] = {};

  const int srow  = tid >> 1;
  const int shalf = (tid & 1) * 16;

  const unsigned short* Ap = A + (rowA0 + srow) * (size_t)K + shalf;
  const unsigned short* Bp = B + (colB0 + srow) * (size_t)K + shalf;

  const int fr = lane & 15;
  const int fk = (lane >> 4) << 3;

  for (int k0 = 0; k0 < K; k0 += 32) {
    short8 a0 = *reinterpret_cast<const short8*>(Ap + k0);
    short8 a1 = *reinterpret_cast<const short8*>(Ap + k0 + 8);
    short8 b0 = *reinterpret_cast<const short8*>(Bp + k0);
    short8 b1 = *reinterpret_cast<const short8*>(Bp + k0 + 8);
    *reinterpret_cast<short8*>(&As[srow][shalf])     = a0;
    *reinterpret_cast<short8*>(&As[srow][shalf + 8]) = a1;
    *reinterpret_cast<short8*>(&Bs[srow][shalf])     = b0;
    *reinterpret_cast<short8*>(&Bs[srow][shalf + 8]) = b1;
    __syncthreads();

    short8 av[4], bv[4];
    #pragma unroll
    for (int mi = 0; mi < 4; ++mi)
      av[mi] = *reinterpret_cast<const short8*>(&As[wm * 64 + mi * 16 + fr][fk]);
    #pragma unroll
    for (int ni = 0; ni < 4; ++ni)
      bv[ni] = *reinterpret_cast<const short8*>(&Bs[wn * 64 + ni * 16 + fr][fk]);
    #pragma unroll
    for (int mi = 0; mi < 4; ++mi)
      #pragma unroll
      for (int ni = 0; ni < 4; ++ni)
        acc[mi][ni] = __builtin_amdgcn_mfma_f32_16x16x32_bf16(av[mi], bv[ni], acc[mi][ni], 0, 0, 0);
    __syncthreads();
  }

  const int orow = (lane >> 4) * 4;
  const int ocol = lane & 15;
  #pragma unroll
  for (int mi = 0; mi < 4; ++mi) {
    #pragma unroll
    for (int ni = 0; ni < 4; ++ni) {
      size_t r0 = rowA0 + wm * 64 + mi * 16 + orow;
      size_t c  = colB0 + wn * 64 + ni * 16 + ocol;
      float bv_ = bias[c];
      #pragma unroll
      for (int j = 0; j < 4; ++j)
        Cout[(r0 + j) * (size_t)N + c] = acc[mi][ni][j] + bv_;
    }
  }
}

// ---------- launch ----------

extern "C" void kernel_launch(void* const* d_in, const int* in_sizes, int n_in,
                              void* d_out, int out_size, void* d_ws, size_t ws_size,
                              hipStream_t stream) {
  const float* x       = (const float*)d_in[0];   // [8192,4096]
  const float* q_w     = (const float*)d_in[1];   // [4096,4096]
  const float* q_b     = (const float*)d_in[2];   // [4096]
  const float* k_cache = (const float*)d_in[3];   // [100,4096]
  const float* v_cache = (const float*)d_in[4];   // [100,4096]
  const float* out_w   = (const float*)d_in[5];   // [4096,4096]
  const float* out_b   = (const float*)d_in[6];   // [4096]
  float* out = (float*)d_out;

  const int M = 8192, H = 4096;

  char* ws = (char*)d_ws;
  size_t off = 0;
  auto alloc = [&](size_t bytes) { void* p = ws + off; off += (bytes + 255) & ~(size_t)255; return p; };
  unsigned short* kpad   = (unsigned short*)alloc((size_t)128 * H * 2);            // 1 MB
  unsigned short* vpad   = (unsigned short*)alloc((size_t)128 * H * 2);            // 1 MB
  float*          sbias  = (float*)alloc(128 * 4);
  unsigned short* KQ2    = (unsigned short*)alloc((size_t)256 * H * 2);            // 2 MB
  unsigned short* W2     = (unsigned short*)alloc((size_t)M * 256 * 2);            // 4 MB
  unsigned short* VOT2   = (unsigned short*)alloc((size_t)H * 256 * 2);            // 2 MB
  float*          KQpart = (float*)alloc((size_t)8 * 128 * H * 4);                 // 16.8 MB
  float*          VOpart = (float*)alloc((size_t)16 * H * 128 * 4);                // 33.6 MB
  float*          Spart  = VOpart;   // S partials (8*8192*128*4 = 33.6 MB) reuse VOpart (dead after reduces)
  if (ws_size < off) { fprintf(stderr, "ws too small: need %zu have %zu\n", off, ws_size); return; }

  // 1) prep: kpad + vpad + sbias (one launch)
  prep<<<4128, 256, 0, stream>>>(k_cache, v_cache, q_b, kpad, vpad, sbias);

  // 2) KQ GEMM (fused transpose+hi/lo) || VO GEMM (counted-vmcnt pipeline) — one launch
  fused_kqvo<<<768, 256, 0, stream>>>(kpad, q_w, KQpart, out_w, vpad, VOpart, H);

  // 3) kq_reduce || vo_reduce — one launch
  reduces<<<4096, 256, 0, stream>>>(KQpart, KQ2, VOpart, VOT2);

  // 4) S = x @ KQ2^T (hi/lo folded in-kernel), pipelined, ksplit 8
  gemm_s<<<dim3(8, 64), 256, 0, stream>>>(x, KQ2, Spart, M, H, 512);

  // 5) softmax -> W2 [8192][256] dup
  softmax_fused2<<<M / 4, 256, 0, stream>>>(Spart, sbias, W2, M);

  // 6) out = W2 @ VOT2^T + out_b (K=256: [W|W] x [hi|lo])
  gemm_final<<<dim3(32, 64), 256, 0, stream>>>(W2, VOT2, out_b, out, M, H, 256);
}